// Round 1
// baseline (258.337 us; speedup 1.0000x reference)
//
#include <hip/hip_runtime.h>

// ---------------------------------------------------------------------------
// GAT (2-layer, dense mask) on gfx950.
// Pipeline:
//  K0 k_adj_pack : adj int32 (4096^2) -> bitmask u64[4096][64]        (2 MB)
//  K1 k_pack_xA  : x f32 -> bf16, MFMA-A layout [f/8][n][8]
//  K1b k_pack_wB : W f32 -> bf16, MFMA-B layout [h][f/8][o][8]
//  K2 k_gemm1    : Wh[h][n][o] = x @ W[h]   (MFMA 16x16x32 bf16)
//  K2b k_pack_whB: Wh f32 -> bf16 MFMA-B layout [h][j/8][o][8]
//  K3 k_scores1  : s1=Wh@a1, s2=Wh@a2 + exp(s), exp(0.2 s) tables
//  K4 k_att1     : h[n][h*64+o] = elu( (sum_j w_ij Wh_j) / (sum_j w_ij) )
//                  w_ij = mask * exp(leakyrelu(s1_i+s2_j))  [no max-sub needed]
//  K5 k_gemm2    : Who = h @ W_out (+ layer-2 score tables + bf16 pack)
//  K6 k_att2     : layer-2 attention, 4-way K-split partials
//  K7 k_final    : combine + elu + log_softmax -> out
// ---------------------------------------------------------------------------

typedef __attribute__((ext_vector_type(8))) short short8;   // 8 x bf16
typedef __attribute__((ext_vector_type(4))) float f32x4;

__device__ __forceinline__ unsigned short f2bf_rne(float f){
  unsigned int u = __float_as_uint(f);
  return (unsigned short)((u + 0x7fffu + ((u >> 16) & 1u)) >> 16);
}

__device__ __forceinline__ void async16(void* lds, const void* g){
  __builtin_amdgcn_global_load_lds((const __attribute__((address_space(1))) unsigned int*)g,
                                   (__attribute__((address_space(3))) unsigned int*)lds, 16, 0, 0);
}
__device__ __forceinline__ void async4(void* lds, const void* g){
  __builtin_amdgcn_global_load_lds((const __attribute__((address_space(1))) unsigned int*)g,
                                   (__attribute__((address_space(3))) unsigned int*)lds, 4, 0, 0);
}

// ------------------------- K0: adj -> bitmask ------------------------------
__global__ __launch_bounds__(256) void k_adj_pack(const int* __restrict__ adj,
                                                  unsigned long long* __restrict__ bits){
  int lane = threadIdx.x & 63;
  int wid  = blockIdx.x * 4 + (threadIdx.x >> 6);
  int i  = wid >> 6;       // row
  int jg = wid & 63;       // 64-col group
  int v = adj[(size_t)i * 4096 + (jg << 6) + lane];
  unsigned long long m = __ballot(v != 0);
  if (lane == 0) bits[(size_t)i * 64 + jg] = m;
}

// ------------------------- K1: pack x to A-layout bf16 ---------------------
// xA element (n,f) at [((f>>3)*4096 + n)*8 + (f&7)]
__global__ __launch_bounds__(256) void k_pack_xA(const float* __restrict__ x,
                                                 unsigned short* __restrict__ xA){
  int tid = blockIdx.x * 256 + threadIdx.x;   // 262144
  int n = tid & 4095;
  int fg = tid >> 12;                          // 0..63
  const float* src = x + (size_t)n * 512 + fg * 8;
  float4 v0 = ((const float4*)src)[0];
  float4 v1 = ((const float4*)src)[1];
  unsigned int pk[4];
  pk[0] = f2bf_rne(v0.x) | ((unsigned)f2bf_rne(v0.y) << 16);
  pk[1] = f2bf_rne(v0.z) | ((unsigned)f2bf_rne(v0.w) << 16);
  pk[2] = f2bf_rne(v1.x) | ((unsigned)f2bf_rne(v1.y) << 16);
  pk[3] = f2bf_rne(v1.z) | ((unsigned)f2bf_rne(v1.w) << 16);
  *(uint4*)(xA + ((size_t)fg * 4096 + n) * 8) = *(uint4*)pk;
}

// ------------------------- K1b: pack W to B-layout bf16 --------------------
// wB element (h,f,o) at [h*32768 + ((f>>3)*64 + o)*8 + (f&7)]
__global__ __launch_bounds__(256) void k_pack_wB(const float* __restrict__ W,
                                                 unsigned short* __restrict__ wB){
  int tid = blockIdx.x * 256 + threadIdx.x;   // 32768
  int o  = tid & 63;
  int fg = (tid >> 6) & 63;
  int h  = tid >> 12;
  const float* src = W + ((size_t)h * 512 + fg * 8) * 64 + o;
  unsigned int pk[4];
  #pragma unroll
  for (int p = 0; p < 4; ++p){
    unsigned short lo = f2bf_rne(src[(2 * p) * 64]);
    unsigned short hi = f2bf_rne(src[(2 * p + 1) * 64]);
    pk[p] = lo | ((unsigned)hi << 16);
  }
  *(uint4*)(wB + (size_t)h * 32768 + ((size_t)fg * 64 + o) * 8) = *(uint4*)pk;
}

// ------------------------- K2: Wh = x @ W[h] (MFMA) ------------------------
__global__ __launch_bounds__(256) void k_gemm1(const unsigned short* __restrict__ xA,
                                               const unsigned short* __restrict__ wB,
                                               float* __restrict__ Whf){
  int h    = blockIdx.y;
  int nblk = blockIdx.x;                  // 0..63
  int lane = threadIdx.x & 63;
  int wid  = threadIdx.x >> 6;
  int row16 = lane & 15, grp = lane >> 4;
  int n0 = nblk * 64 + wid * 16;
  const unsigned short* wBh = wB + (size_t)h * 32768;
  f32x4 acc[4] = {};
  #pragma unroll 4
  for (int ks = 0; ks < 16; ++ks){        // 32 f's per step
    int fgb = ks * 4 + grp;               // f>>3 for this lane
    short8 af = *(const short8*)(xA + ((size_t)fgb * 4096 + n0 + row16) * 8);
    #pragma unroll
    for (int nt = 0; nt < 4; ++nt){
      short8 bf = *(const short8*)(wBh + ((size_t)fgb * 64 + nt * 16 + row16) * 8);
      acc[nt] = __builtin_amdgcn_mfma_f32_16x16x32_bf16(af, bf, acc[nt], 0, 0, 0);
    }
  }
  #pragma unroll
  for (int nt = 0; nt < 4; ++nt)
    #pragma unroll
    for (int r = 0; r < 4; ++r){
      int n = n0 + grp * 4 + r;
      int o = nt * 16 + row16;
      Whf[((size_t)h * 4096 + n) * 64 + o] = acc[nt][r];
    }
}

// ------------------------- K2b: pack Wh to B-layout bf16 -------------------
// whB element (h,j,o) at [h*262144 + ((j>>3)*64 + o)*8 + (j&7)]
__global__ __launch_bounds__(256) void k_pack_whB(const float* __restrict__ Whf,
                                                  unsigned short* __restrict__ whB){
  int tid = blockIdx.x * 256 + threadIdx.x;   // 262144
  int o  = tid & 63;
  int jg = (tid >> 6) & 511;
  int h  = tid >> 15;
  const float* src = Whf + ((size_t)h * 4096 + jg * 8) * 64 + o;
  unsigned int pk[4];
  #pragma unroll
  for (int p = 0; p < 4; ++p){
    unsigned short lo = f2bf_rne(src[(2 * p) * 64]);
    unsigned short hi = f2bf_rne(src[(2 * p + 1) * 64]);
    pk[p] = lo | ((unsigned)hi << 16);
  }
  *(uint4*)(whB + (size_t)h * 262144 + ((size_t)jg * 64 + o) * 8) = *(uint4*)pk;
}

// ------------------------- K3: layer-1 score tables ------------------------
__global__ __launch_bounds__(256) void k_scores1(const float* __restrict__ Whf,
                                                 const float* __restrict__ av,
                                                 float* __restrict__ s1raw, float* __restrict__ e11,
                                                 float* __restrict__ e102, float* __restrict__ s2raw,
                                                 float* __restrict__ e21, float* __restrict__ e202){
  int lane = threadIdx.x & 63;
  int wid  = blockIdx.x * 4 + (threadIdx.x >> 6);   // 32768 waves
  int h = wid >> 12;
  int i = wid & 4095;
  float wh = Whf[((size_t)h * 4096 + i) * 64 + lane];
  float p1 = wh * av[h * 128 + lane];
  float p2 = wh * av[h * 128 + 64 + lane];
  #pragma unroll
  for (int d = 32; d; d >>= 1){ p1 += __shfl_xor(p1, d, 64); p2 += __shfl_xor(p2, d, 64); }
  if (lane == 0){
    int idx = h * 4096 + i;
    s1raw[idx] = p1; e11[idx] = __expf(p1); e102[idx] = __expf(0.2f * p1);
    s2raw[idx] = p2; e21[idx] = __expf(p2); e202[idx] = __expf(0.2f * p2);
  }
}

// ------------------------- K4: layer-1 fused attention ---------------------
__global__ __launch_bounds__(256) void k_att1(const unsigned short* __restrict__ whB,
                                              const unsigned long long* __restrict__ adjbits,
                                              const float* __restrict__ s1raw, const float* __restrict__ e11,
                                              const float* __restrict__ e102, const float* __restrict__ s2raw,
                                              const float* __restrict__ e21, const float* __restrict__ e202,
                                              float* __restrict__ hmat){
  __shared__ unsigned short smB[4096];          // 64 j x 64 o, packed [j/8][o][8]
  __shared__ float smS2[64], smE21[64], smE202[64];
  int h    = blockIdx.y;
  int iblk = blockIdx.x;                        // 0..63
  int lane = threadIdx.x & 63;
  int wid  = threadIdx.x >> 6;
  int row16 = lane & 15, grp = lane >> 4;
  int i = iblk * 64 + wid * 16 + row16;         // A-fragment row for this lane
  int hoff = h * 4096;
  float s1  = s1raw[hoff + i];
  float f1  = e11[hoff + i];
  float f02 = e102[hoff + i];
  const unsigned short* whBh = whB + (size_t)h * 262144;
  f32x4 acc[4] = {};
  float den = 0.f;

  for (int j0 = 0; j0 < 4096; j0 += 64){
    __syncthreads();                            // previous chunk fully consumed
    {
      const char* gB = (const char*)whBh + (size_t)j0 * 128;   // chunk is contiguous 8192 B
      char* lB = (char*)smB + wid * 2048;
      const char* gw = gB + wid * 2048 + lane * 16;
      async16(lB, gw);
      async16(lB + 1024, gw + 1024);
      if (wid == 0)      async4(smS2,  (const char*)(s2raw + hoff + j0) + lane * 4);
      else if (wid == 1) async4(smE21, (const char*)(e21  + hoff + j0) + lane * 4);
      else if (wid == 2) async4(smE202,(const char*)(e202 + hoff + j0) + lane * 4);
    }
    unsigned long long mrow = adjbits[(size_t)i * 64 + (j0 >> 6)];
    __syncthreads();                            // stages complete (vmcnt drained)

    #pragma unroll
    for (int ks = 0; ks < 2; ++ks){
      int kb = ks * 32 + grp * 8;
      float4 sA = *(const float4*)(smS2 + kb);
      float4 sB = *(const float4*)(smS2 + kb + 4);
      float4 eA = *(const float4*)(smE21 + kb);
      float4 eB = *(const float4*)(smE21 + kb + 4);
      float4 gA = *(const float4*)(smE202 + kb);
      float4 gB2 = *(const float4*)(smE202 + kb + 4);
      float sv[8]  = {sA.x, sA.y, sA.z, sA.w, sB.x, sB.y, sB.z, sB.w};
      float e1v[8] = {eA.x, eA.y, eA.z, eA.w, eB.x, eB.y, eB.z, eB.w};
      float e2v[8] = {gA.x, gA.y, gA.z, gA.w, gB2.x, gB2.y, gB2.z, gB2.w};
      unsigned int mb = ((unsigned int)(mrow >> (ks * 32)) >> (grp * 8)) & 0xffu;
      short8 af;
      #pragma unroll
      for (int t = 0; t < 8; ++t){
        float tt = s1 + sv[t];
        float w = (tt > 0.f) ? (f1 * e1v[t]) : (f02 * e2v[t]);
        w = ((mb >> t) & 1u) ? w : 0.f;
        den += w;
        af[t] = (short)(__float_as_uint(w) >> 16);   // bf16 truncate (w>=0, bias ~ -0.2% cancels in num/den)
      }
      const unsigned short* bbase = smB + (size_t)(ks * 4 + grp) * 512;
      #pragma unroll
      for (int nt = 0; nt < 4; ++nt){
        short8 bf = *(const short8*)(bbase + (nt * 16 + row16) * 8);
        acc[nt] = __builtin_amdgcn_mfma_f32_16x16x32_bf16(af, bf, acc[nt], 0, 0, 0);
      }
    }
  }

  // denominator: sum the 4 lane-groups per row (A rows live at lane&15)
  den += __shfl_xor(den, 16, 64);
  den += __shfl_xor(den, 32, 64);
  #pragma unroll
  for (int r = 0; r < 4; ++r){
    float dr = __shfl(den, grp * 4 + r, 64);    // den for C/D row (grp*4+r)
    int n = iblk * 64 + wid * 16 + grp * 4 + r;
    float* dst = hmat + (size_t)n * 512 + h * 64 + row16;
    #pragma unroll
    for (int nt = 0; nt < 4; ++nt){
      float v = acc[nt][r] / dr;
      v = v > 0.f ? v : (__expf(v) - 1.f);      // elu
      dst[nt * 16] = v;
    }
  }
}

// ------------------------- K5: Who = h @ W_out + layer-2 tables ------------
__global__ __launch_bounds__(256) void k_gemm2(const float* __restrict__ hmat,
                                               const float* __restrict__ Wout,
                                               const float* __restrict__ aout,
                                               float* __restrict__ Who, unsigned short* __restrict__ whoB,
                                               float* __restrict__ s1o, float* __restrict__ e11o,
                                               float* __restrict__ e102o, float* __restrict__ s2o,
                                               float* __restrict__ e21o, float* __restrict__ e202o){
  __shared__ float Wl[8192];                    // 512 x 16
  for (int t = threadIdx.x; t < 8192; t += 256) Wl[t] = Wout[t];
  __syncthreads();
  int c  = threadIdx.x & 15;
  int rl = threadIdx.x >> 4;                    // 0..15
  int n = blockIdx.x * 16 + rl;
  const float4* hrow = (const float4*)(hmat + (size_t)n * 512);
  float acc = 0.f;
  #pragma unroll 8
  for (int f4 = 0; f4 < 128; ++f4){
    float4 hv = hrow[f4];
    int f = f4 * 4;
    acc += hv.x * Wl[f * 16 + c] + hv.y * Wl[(f + 1) * 16 + c]
         + hv.z * Wl[(f + 2) * 16 + c] + hv.w * Wl[(f + 3) * 16 + c];
  }
  Who[(size_t)n * 16 + c] = acc;
  whoB[((size_t)(n >> 3) * 16 + c) * 8 + (n & 7)] = f2bf_rne(acc);
  float p1 = acc * aout[c], p2 = acc * aout[16 + c];
  #pragma unroll
  for (int d = 1; d < 16; d <<= 1){ p1 += __shfl_xor(p1, d, 64); p2 += __shfl_xor(p2, d, 64); }
  if (c == 0){
    s1o[n] = p1; e11o[n] = __expf(p1); e102o[n] = __expf(0.2f * p1);
    s2o[n] = p2; e21o[n] = __expf(p2); e202o[n] = __expf(0.2f * p2);
  }
}

// ------------------------- K6: layer-2 attention (K-split 4) ---------------
__global__ __launch_bounds__(256) void k_att2(const unsigned short* __restrict__ whoB,
                                              const unsigned long long* __restrict__ adjbits,
                                              const float* __restrict__ s1o, const float* __restrict__ e11o,
                                              const float* __restrict__ e102o, const float* __restrict__ s2o,
                                              const float* __restrict__ e21o, const float* __restrict__ e202o,
                                              float* __restrict__ pnum, float* __restrict__ pden){
  __shared__ unsigned short smB[1024];          // 64 j x 16 c
  __shared__ float smS2[64], smE21[64], smE202[64];
  int iblk  = blockIdx.x;
  int split = blockIdx.y;
  int lane = threadIdx.x & 63;
  int wid  = threadIdx.x >> 6;
  int row16 = lane & 15, grp = lane >> 4;
  int i = iblk * 64 + wid * 16 + row16;
  float s1  = s1o[i];
  float f1  = e11o[i];
  float f02 = e102o[i];
  f32x4 acc = {};
  float den = 0.f;
  int jbeg = split * 1024;
  for (int j0 = jbeg; j0 < jbeg + 1024; j0 += 64){
    __syncthreads();
    {
      const char* gB = (const char*)whoB + (size_t)j0 * 32;    // chunk contiguous 2048 B
      if (wid == 0){
        async16((char*)smB, gB + lane * 16);
        async16((char*)smB + 1024, gB + 1024 + lane * 16);
      }
      else if (wid == 1) async4(smS2,  (const char*)(s2o  + j0) + lane * 4);
      else if (wid == 2) async4(smE21, (const char*)(e21o + j0) + lane * 4);
      else               async4(smE202,(const char*)(e202o + j0) + lane * 4);
    }
    unsigned long long mrow = adjbits[(size_t)i * 64 + (j0 >> 6)];
    __syncthreads();
    #pragma unroll
    for (int ks = 0; ks < 2; ++ks){
      int kb = ks * 32 + grp * 8;
      float4 sA = *(const float4*)(smS2 + kb);
      float4 sB = *(const float4*)(smS2 + kb + 4);
      float4 eA = *(const float4*)(smE21 + kb);
      float4 eB = *(const float4*)(smE21 + kb + 4);
      float4 gA = *(const float4*)(smE202 + kb);
      float4 gB2 = *(const float4*)(smE202 + kb + 4);
      float sv[8]  = {sA.x, sA.y, sA.z, sA.w, sB.x, sB.y, sB.z, sB.w};
      float e1v[8] = {eA.x, eA.y, eA.z, eA.w, eB.x, eB.y, eB.z, eB.w};
      float e2v[8] = {gA.x, gA.y, gA.z, gA.w, gB2.x, gB2.y, gB2.z, gB2.w};
      unsigned int mb = ((unsigned int)(mrow >> (ks * 32)) >> (grp * 8)) & 0xffu;
      short8 af;
      #pragma unroll
      for (int t = 0; t < 8; ++t){
        float tt = s1 + sv[t];
        float w = (tt > 0.f) ? (f1 * e1v[t]) : (f02 * e2v[t]);
        w = ((mb >> t) & 1u) ? w : 0.f;
        den += w;
        af[t] = (short)(__float_as_uint(w) >> 16);
      }
      short8 bf = *(const short8*)(smB + (size_t)((ks * 4 + grp) * 16 + row16) * 8);
      acc = __builtin_amdgcn_mfma_f32_16x16x32_bf16(af, bf, acc, 0, 0, 0);
    }
  }
  den += __shfl_xor(den, 16, 64);
  den += __shfl_xor(den, 32, 64);
  #pragma unroll
  for (int r = 0; r < 4; ++r){
    float dr = __shfl(den, grp * 4 + r, 64);
    int n = iblk * 64 + wid * 16 + grp * 4 + r;
    pnum[((size_t)split * 4096 + n) * 16 + row16] = acc[r];
    if (row16 == 0) pden[(size_t)split * 4096 + n] = dr;
  }
}

// ------------------------- K7: combine + elu + log_softmax -----------------
__global__ __launch_bounds__(256) void k_final(const float* __restrict__ pnum,
                                               const float* __restrict__ pden,
                                               float* __restrict__ out){
  int tid = blockIdx.x * 256 + threadIdx.x;     // 65536
  int c = tid & 15;
  int n = tid >> 4;
  float num = 0.f, den = 0.f;
  #pragma unroll
  for (int s = 0; s < 4; ++s){
    num += pnum[((size_t)s * 4096 + n) * 16 + c];
    den += pden[(size_t)s * 4096 + n];
  }
  float v = num / den;
  v = v > 0.f ? v : (__expf(v) - 1.f);
  float m = v;
  #pragma unroll
  for (int d = 1; d < 16; d <<= 1) m = fmaxf(m, __shfl_xor(m, d, 64));
  float es = __expf(v - m), ss = es;
  #pragma unroll
  for (int d = 1; d < 16; d <<= 1) ss += __shfl_xor(ss, d, 64);
  out[(size_t)n * 16 + c] = v - m - __logf(ss);
}

// ---------------------------------------------------------------------------
extern "C" void kernel_launch(void* const* d_in, const int* in_sizes, int n_in,
                              void* d_out, int out_size, void* d_ws, size_t ws_size,
                              hipStream_t stream){
  (void)in_sizes; (void)n_in; (void)out_size; (void)ws_size;
  const float* x    = (const float*)d_in[0];
  const int*   adj  = (const int*)d_in[1];
  const float* W    = (const float*)d_in[2];
  const float* av   = (const float*)d_in[3];
  const float* Wout = (const float*)d_in[4];
  const float* aout = (const float*)d_in[5];
  float* out = (float*)d_out;
  char* ws = (char*)d_ws;

  unsigned long long* adjbits = (unsigned long long*)(ws + 0x0000000); // 2 MB
  unsigned short* xA   = (unsigned short*)(ws + 0x0200000);            // 4 MB
  unsigned short* wB   = (unsigned short*)(ws + 0x0600000);            // 512 KB
  float* Whf           = (float*)(ws + 0x0680000);                     // 8 MB
  unsigned short* whB  = (unsigned short*)(ws + 0x0E80000);            // 4 MB
  float* s1raw = (float*)(ws + 0x1280000);                             // 6 x 128 KB
  float* e11   = (float*)(ws + 0x12A0000);
  float* e102  = (float*)(ws + 0x12C0000);
  float* s2raw = (float*)(ws + 0x12E0000);
  float* e21   = (float*)(ws + 0x1300000);
  float* e202  = (float*)(ws + 0x1320000);
  float* hmat  = (float*)(ws + 0x1340000);                             // 8 MB
  float* Who   = (float*)(ws + 0x1B40000);                             // 256 KB
  unsigned short* whoB = (unsigned short*)(ws + 0x1B80000);            // 128 KB
  float* s1o   = (float*)(ws + 0x1BA0000);                             // 6 x 16 KB
  float* e11o  = (float*)(ws + 0x1BA4000);
  float* e102o = (float*)(ws + 0x1BA8000);
  float* s2o   = (float*)(ws + 0x1BAC000);
  float* e21o  = (float*)(ws + 0x1BB0000);
  float* e202o = (float*)(ws + 0x1BB4000);
  float* pnum  = (float*)(ws + 0x1BC0000);                             // 1 MB
  float* pden  = (float*)(ws + 0x1CC0000);                             // 64 KB

  k_adj_pack<<<dim3(65536), dim3(256), 0, stream>>>(adj, adjbits);
  k_pack_xA<<<dim3(1024), dim3(256), 0, stream>>>(x, xA);
  k_pack_wB<<<dim3(128), dim3(256), 0, stream>>>(W, wB);
  k_gemm1<<<dim3(64, 8), dim3(256), 0, stream>>>(xA, wB, Whf);
  k_pack_whB<<<dim3(1024), dim3(256), 0, stream>>>(Whf, whB);
  k_scores1<<<dim3(8192), dim3(256), 0, stream>>>(Whf, av, s1raw, e11, e102, s2raw, e21, e202);
  k_att1<<<dim3(64, 8), dim3(256), 0, stream>>>(whB, adjbits, s1raw, e11, e102, s2raw, e21, e202, hmat);
  k_gemm2<<<dim3(256), dim3(256), 0, stream>>>(hmat, Wout, aout, Who, whoB, s1o, e11o, e102o, s2o, e21o, e202o);
  k_att2<<<dim3(64, 4), dim3(256), 0, stream>>>(whoB, adjbits, s1o, e11o, e102o, s2o, e21o, e202o, pnum, pden);
  k_final<<<dim3(256), dim3(256), 0, stream>>>(pnum, pden, out);
}

// Round 2
// 208.145 us; speedup vs baseline: 1.2411x; 1.2411x over previous
//
#include <hip/hip_runtime.h>

// ---------------------------------------------------------------------------
// GAT (2-layer, dense mask) on gfx950 — R2.
// Changes vs R1: k_att1 4-way j-split (2048 blocks, full occupancy) with
// single-barrier double-buffered staging; bf16 num partials combined inside
// k_gemm2 prologue; k_att2 16-way split + dbuf; adj_pack 16 rows/block;
// launches fused 10 -> 8.
// ---------------------------------------------------------------------------

typedef __attribute__((ext_vector_type(8))) short short8;   // 8 x bf16
typedef __attribute__((ext_vector_type(4))) float f32x4;
typedef unsigned long long u64;
typedef unsigned short u16;

__device__ __forceinline__ u16 f2bf_rne(float f){
  unsigned int u = __float_as_uint(f);
  return (u16)((u + 0x7fffu + ((u >> 16) & 1u)) >> 16);
}
__device__ __forceinline__ float bf2f(u16 v){
  return __uint_as_float(((unsigned int)v) << 16);
}
__device__ __forceinline__ void async16(void* lds, const void* g){
  __builtin_amdgcn_global_load_lds((const __attribute__((address_space(1))) unsigned int*)g,
                                   (__attribute__((address_space(3))) unsigned int*)lds, 16, 0, 0);
}
__device__ __forceinline__ void async4(void* lds, const void* g){
  __builtin_amdgcn_global_load_lds((const __attribute__((address_space(1))) unsigned int*)g,
                                   (__attribute__((address_space(3))) unsigned int*)lds, 4, 0, 0);
}

// ------------------------- K0: adj -> bitmask (16 row-groups per block) ----
__global__ __launch_bounds__(256) void k_adj_pack(const int* __restrict__ adj,
                                                  u64* __restrict__ bits){
  int lane = threadIdx.x & 63;
  int w0 = blockIdx.x * 4 + (threadIdx.x >> 6);       // 0..16383
  #pragma unroll
  for (int k = 0; k < 16; ++k){
    int wid = w0 + k * 16384;
    int i  = wid >> 6;
    int jg = wid & 63;
    int v = adj[(size_t)i * 4096 + (jg << 6) + lane];
    u64 m = __ballot(v != 0);
    if (lane == 0) bits[(size_t)i * 64 + jg] = m;
  }
}

// ------------------------- K1: pack x->A-layout + W->B-layout --------------
// xA (n,f) at [((f>>3)*4096 + n)*8 + (f&7)] ; wB (h,f,o) at [h*32768+((f>>3)*64+o)*8+(f&7)]
__global__ __launch_bounds__(256) void k_pack_in(const float* __restrict__ x,
                                                 const float* __restrict__ W,
                                                 u16* __restrict__ xA,
                                                 u16* __restrict__ wB){
  if (blockIdx.x < 1024){
    int tid = blockIdx.x * 256 + threadIdx.x;         // 262144
    int n = tid & 4095;
    int fg = tid >> 12;
    const float* src = x + (size_t)n * 512 + fg * 8;
    float4 v0 = ((const float4*)src)[0];
    float4 v1 = ((const float4*)src)[1];
    unsigned int pk[4];
    pk[0] = f2bf_rne(v0.x) | ((unsigned)f2bf_rne(v0.y) << 16);
    pk[1] = f2bf_rne(v0.z) | ((unsigned)f2bf_rne(v0.w) << 16);
    pk[2] = f2bf_rne(v1.x) | ((unsigned)f2bf_rne(v1.y) << 16);
    pk[3] = f2bf_rne(v1.z) | ((unsigned)f2bf_rne(v1.w) << 16);
    *(uint4*)(xA + ((size_t)fg * 4096 + n) * 8) = *(uint4*)pk;
  } else {
    int tid = (blockIdx.x - 1024) * 256 + threadIdx.x; // 32768
    int o  = tid & 63;
    int fg = (tid >> 6) & 63;
    int h  = tid >> 12;
    const float* src = W + ((size_t)h * 512 + fg * 8) * 64 + o;
    unsigned int pk[4];
    #pragma unroll
    for (int p = 0; p < 4; ++p){
      u16 lo = f2bf_rne(src[(2 * p) * 64]);
      u16 hi = f2bf_rne(src[(2 * p + 1) * 64]);
      pk[p] = lo | ((unsigned)hi << 16);
    }
    *(uint4*)(wB + (size_t)h * 32768 + ((size_t)fg * 64 + o) * 8) = *(uint4*)pk;
  }
}

// ------------------------- K2: Wh = x @ W[h] (MFMA) ------------------------
__global__ __launch_bounds__(256) void k_gemm1(const u16* __restrict__ xA,
                                               const u16* __restrict__ wB,
                                               float* __restrict__ Whf){
  int h    = blockIdx.y;
  int nblk = blockIdx.x;
  int lane = threadIdx.x & 63;
  int wid  = threadIdx.x >> 6;
  int row16 = lane & 15, grp = lane >> 4;
  int n0 = nblk * 64 + wid * 16;
  const u16* wBh = wB + (size_t)h * 32768;
  f32x4 acc[4] = {};
  #pragma unroll 4
  for (int ks = 0; ks < 16; ++ks){
    int fgb = ks * 4 + grp;
    short8 af = *(const short8*)(xA + ((size_t)fgb * 4096 + n0 + row16) * 8);
    #pragma unroll
    for (int nt = 0; nt < 4; ++nt){
      short8 bf = *(const short8*)(wBh + ((size_t)fgb * 64 + nt * 16 + row16) * 8);
      acc[nt] = __builtin_amdgcn_mfma_f32_16x16x32_bf16(af, bf, acc[nt], 0, 0, 0);
    }
  }
  #pragma unroll
  for (int nt = 0; nt < 4; ++nt)
    #pragma unroll
    for (int r = 0; r < 4; ++r){
      int n = n0 + grp * 4 + r;
      int o = nt * 16 + row16;
      Whf[((size_t)h * 4096 + n) * 64 + o] = acc[nt][r];
    }
}

// ------------------------- K3: pack Wh->B-layout + score tables ------------
__global__ __launch_bounds__(256) void k_prep1(const float* __restrict__ Whf,
                                               const float* __restrict__ av,
                                               u16* __restrict__ whB,
                                               float* __restrict__ s1raw, float* __restrict__ e11,
                                               float* __restrict__ e102, float* __restrict__ s2raw,
                                               float* __restrict__ e21, float* __restrict__ e202){
  if (blockIdx.x < 1024){
    int tid = blockIdx.x * 256 + threadIdx.x;   // 262144
    int o  = tid & 63;
    int jg = (tid >> 6) & 511;
    int h  = tid >> 15;
    const float* src = Whf + ((size_t)h * 4096 + jg * 8) * 64 + o;
    unsigned int pk[4];
    #pragma unroll
    for (int p = 0; p < 4; ++p){
      u16 lo = f2bf_rne(src[(2 * p) * 64]);
      u16 hi = f2bf_rne(src[(2 * p + 1) * 64]);
      pk[p] = lo | ((unsigned)hi << 16);
    }
    *(uint4*)(whB + (size_t)h * 262144 + ((size_t)jg * 64 + o) * 8) = *(uint4*)pk;
  } else {
    int lane = threadIdx.x & 63;
    int wid  = (blockIdx.x - 1024) * 4 + (threadIdx.x >> 6);   // 0..32767
    int h = wid >> 12;
    int i = wid & 4095;
    float wh = Whf[((size_t)h * 4096 + i) * 64 + lane];
    float p1 = wh * av[h * 128 + lane];
    float p2 = wh * av[h * 128 + 64 + lane];
    #pragma unroll
    for (int d = 32; d; d >>= 1){ p1 += __shfl_xor(p1, d, 64); p2 += __shfl_xor(p2, d, 64); }
    if (lane == 0){
      int idx = h * 4096 + i;
      s1raw[idx] = p1; e11[idx] = __expf(p1); e102[idx] = __expf(0.2f * p1);
      s2raw[idx] = p2; e21[idx] = __expf(p2); e202[idx] = __expf(0.2f * p2);
    }
  }
}

// ------------------------- K4: layer-1 attention (4-way j-split, dbuf) -----
// B staged in 8 padded sub-blocks of 520 shorts (1040 B) to break the 4-way
// ds_read_b128 bank conflict between lane groups.
__global__ __launch_bounds__(256) void k_att1(const u16* __restrict__ whB,
                                              const u64* __restrict__ adjbits,
                                              const float* __restrict__ s1raw, const float* __restrict__ e11,
                                              const float* __restrict__ e102, const float* __restrict__ s2raw,
                                              const float* __restrict__ e21, const float* __restrict__ e202,
                                              u16* __restrict__ pnum, float* __restrict__ pden){
  __shared__ u16  smB[2][8 * 520];
  __shared__ float smT[2][3][64];
  int h     = blockIdx.y;
  int iblk  = blockIdx.x;
  int split = blockIdx.z;
  int lane = threadIdx.x & 63;
  int wid  = threadIdx.x >> 6;
  int row16 = lane & 15, grp = lane >> 4;
  int i = iblk * 64 + wid * 16 + row16;
  int hoff = h * 4096;
  float s1  = s1raw[hoff + i];
  float f1  = e11[hoff + i];
  float f02 = e102[hoff + i];
  const u16* whBh = whB + (size_t)h * 262144;
  int jbeg = split * 1024;

  auto stage = [&](int b, int j0){
    const char* g = (const char*)whBh + (size_t)j0 * 128 + wid * 2048 + lane * 16;
    char* l = (char*)(&smB[b][0]) + wid * 2 * 1040;          // wave-uniform base
    async16(l, g);
    async16(l + 1040, g + 1024);
    if (wid == 0)      async4(&smT[b][0][0], (const char*)(s2raw + hoff + j0) + lane * 4);
    else if (wid == 1) async4(&smT[b][1][0], (const char*)(e21  + hoff + j0) + lane * 4);
    else if (wid == 2) async4(&smT[b][2][0], (const char*)(e202 + hoff + j0) + lane * 4);
  };

  f32x4 acc[4] = {};
  float den = 0.f;
  stage(0, jbeg);
  for (int c = 0; c < 16; ++c){
    int b = c & 1;
    __syncthreads();                          // buf b staged; buf b^1 free
    if (c < 15) stage(b ^ 1, jbeg + (c + 1) * 64);
    u64 mrow = adjbits[(size_t)i * 64 + ((jbeg + c * 64) >> 6)];
    #pragma unroll
    for (int ks = 0; ks < 2; ++ks){
      int kb = ks * 32 + grp * 8;
      float4 sA = *(const float4*)(&smT[b][0][kb]);
      float4 sB = *(const float4*)(&smT[b][0][kb + 4]);
      float4 eA = *(const float4*)(&smT[b][1][kb]);
      float4 eB = *(const float4*)(&smT[b][1][kb + 4]);
      float4 gA = *(const float4*)(&smT[b][2][kb]);
      float4 gB2 = *(const float4*)(&smT[b][2][kb + 4]);
      float sv[8]  = {sA.x, sA.y, sA.z, sA.w, sB.x, sB.y, sB.z, sB.w};
      float e1v[8] = {eA.x, eA.y, eA.z, eA.w, eB.x, eB.y, eB.z, eB.w};
      float e2v[8] = {gA.x, gA.y, gA.z, gA.w, gB2.x, gB2.y, gB2.z, gB2.w};
      unsigned int mb = ((unsigned int)(mrow >> (ks * 32)) >> (grp * 8)) & 0xffu;
      unsigned int pk[4];
      #pragma unroll
      for (int t2 = 0; t2 < 4; ++t2){
        float w0, w1;
        {
          float tt = s1 + sv[2 * t2];
          float w = (tt > 0.f) ? (f1 * e1v[2 * t2]) : (f02 * e2v[2 * t2]);
          w = ((mb >> (2 * t2)) & 1u) ? w : 0.f;
          den += w; w0 = w;
        }
        {
          float tt = s1 + sv[2 * t2 + 1];
          float w = (tt > 0.f) ? (f1 * e1v[2 * t2 + 1]) : (f02 * e2v[2 * t2 + 1]);
          w = ((mb >> (2 * t2 + 1)) & 1u) ? w : 0.f;
          den += w; w1 = w;
        }
        pk[t2] = __builtin_amdgcn_perm(__float_as_uint(w1), __float_as_uint(w0), 0x07060302u);
      }
      short8 af = *(short8*)pk;
      const u16* bbase = &smB[b][(ks * 4 + grp) * 520];
      #pragma unroll
      for (int nt = 0; nt < 4; ++nt){
        short8 bf = *(const short8*)(bbase + (nt * 16 + row16) * 8);
        acc[nt] = __builtin_amdgcn_mfma_f32_16x16x32_bf16(af, bf, acc[nt], 0, 0, 0);
      }
    }
  }

  den += __shfl_xor(den, 16, 64);
  den += __shfl_xor(den, 32, 64);
  if (grp == 0)
    pden[((size_t)split * 8 + h) * 4096 + iblk * 64 + wid * 16 + row16] = den;
  #pragma unroll
  for (int r = 0; r < 4; ++r){
    int n = iblk * 64 + wid * 16 + grp * 4 + r;
    u16* dst = pnum + ((size_t)split * 4096 + n) * 512 + h * 64 + row16;
    #pragma unroll
    for (int nt = 0; nt < 4; ++nt)
      dst[nt * 16] = f2bf_rne(acc[nt][r]);
  }
}

// ------------------------- K5: combine + Who=h@Wout + layer-2 tables -------
__global__ __launch_bounds__(256) void k_gemm2(const u16* __restrict__ pnum,
                                               const float* __restrict__ pden,
                                               const float* __restrict__ Wout,
                                               const float* __restrict__ aout,
                                               u16* __restrict__ whoB,
                                               float* __restrict__ s1o, float* __restrict__ e11o,
                                               float* __restrict__ e102o, float* __restrict__ s2o,
                                               float* __restrict__ e21o, float* __restrict__ e202o){
  __shared__ float Wl[8192];                  // 512 x 16
  __shared__ float hrow[16 * 516];            // combined+elu rows, padded stride
  __shared__ float sden[128];                 // den[h][n]
  int n0 = blockIdx.x * 16;
  for (int t = threadIdx.x; t < 8192; t += 256) Wl[t] = Wout[t];
  if (threadIdx.x < 128){
    int hh = threadIdx.x >> 4, nn = threadIdx.x & 15;
    float d = 0.f;
    #pragma unroll
    for (int s = 0; s < 4; ++s) d += pden[((size_t)s * 8 + hh) * 4096 + n0 + nn];
    sden[threadIdx.x] = d;
  }
  __syncthreads();
  {
    int nn = threadIdx.x >> 4;                // row 0..15
    int fc = threadIdx.x & 15;                // 32-f chunk
    int f0 = fc * 32;
    int hh = fc >> 1;
    float dinv = 1.f / sden[hh * 16 + nn];
    float v[32];
    #pragma unroll
    for (int k = 0; k < 32; ++k) v[k] = 0.f;
    #pragma unroll
    for (int s = 0; s < 4; ++s){
      const u16* p = pnum + ((size_t)s * 4096 + n0 + nn) * 512 + f0;
      #pragma unroll
      for (int q = 0; q < 4; ++q){
        uint4 raw = *(const uint4*)(p + q * 8);
        unsigned int rw[4] = {raw.x, raw.y, raw.z, raw.w};
        #pragma unroll
        for (int d2 = 0; d2 < 4; ++d2){
          v[q * 8 + d2 * 2]     += __uint_as_float(rw[d2] << 16);
          v[q * 8 + d2 * 2 + 1] += __uint_as_float(rw[d2] & 0xffff0000u);
        }
      }
    }
    #pragma unroll
    for (int k = 0; k < 32; ++k){
      float val = v[k] * dinv;
      val = val > 0.f ? val : (__expf(val) - 1.f);
      hrow[nn * 516 + f0 + k] = val;
    }
  }
  __syncthreads();
  int c  = threadIdx.x & 15;
  int rl = threadIdx.x >> 4;                  // 0..15
  int n = n0 + rl;
  const float4* hr = (const float4*)(hrow + rl * 516);
  float acc = 0.f;
  #pragma unroll 8
  for (int f4 = 0; f4 < 128; ++f4){
    float4 hv = hr[f4];
    int f = f4 * 4;
    acc += hv.x * Wl[f * 16 + c] + hv.y * Wl[(f + 1) * 16 + c]
         + hv.z * Wl[(f + 2) * 16 + c] + hv.w * Wl[(f + 3) * 16 + c];
  }
  whoB[((size_t)(n >> 3) * 16 + c) * 8 + (n & 7)] = f2bf_rne(acc);
  float p1 = acc * aout[c], p2 = acc * aout[16 + c];
  #pragma unroll
  for (int d = 1; d < 16; d <<= 1){ p1 += __shfl_xor(p1, d, 64); p2 += __shfl_xor(p2, d, 64); }
  if (c == 0){
    s1o[n] = p1; e11o[n] = __expf(p1); e102o[n] = __expf(0.2f * p1);
    s2o[n] = p2; e21o[n] = __expf(p2); e202o[n] = __expf(0.2f * p2);
  }
}

// ------------------------- K6: layer-2 attention (16-way split, dbuf) ------
__global__ __launch_bounds__(256) void k_att2(const u16* __restrict__ whoB,
                                              const u64* __restrict__ adjbits,
                                              const float* __restrict__ s1o, const float* __restrict__ e11o,
                                              const float* __restrict__ e102o, const float* __restrict__ s2o,
                                              const float* __restrict__ e21o, const float* __restrict__ e202o,
                                              float* __restrict__ pnum, float* __restrict__ pden){
  __shared__ u16  smB[2][1024];
  __shared__ float smT[2][3][64];
  int iblk  = blockIdx.x;
  int split = blockIdx.y;                     // 0..15
  int lane = threadIdx.x & 63;
  int wid  = threadIdx.x >> 6;
  int row16 = lane & 15, grp = lane >> 4;
  int i = iblk * 64 + wid * 16 + row16;
  float s1  = s1o[i];
  float f1  = e11o[i];
  float f02 = e102o[i];
  int jbeg = split * 256;

  auto stage = [&](int b, int j0){
    const char* gB = (const char*)whoB + (size_t)j0 * 32;
    if (wid == 0){
      async16((char*)&smB[b][0], gB + lane * 16);
      async16((char*)&smB[b][0] + 1024, gB + 1024 + lane * 16);
    }
    else if (wid == 1) async4(&smT[b][0][0], (const char*)(s2o  + j0) + lane * 4);
    else if (wid == 2) async4(&smT[b][1][0], (const char*)(e21o + j0) + lane * 4);
    else               async4(&smT[b][2][0], (const char*)(e202o + j0) + lane * 4);
  };

  f32x4 acc = {};
  float den = 0.f;
  stage(0, jbeg);
  for (int c = 0; c < 4; ++c){
    int b = c & 1;
    __syncthreads();
    if (c < 3) stage(b ^ 1, jbeg + (c + 1) * 64);
    u64 mrow = adjbits[(size_t)i * 64 + ((jbeg + c * 64) >> 6)];
    #pragma unroll
    for (int ks = 0; ks < 2; ++ks){
      int kb = ks * 32 + grp * 8;
      float4 sA = *(const float4*)(&smT[b][0][kb]);
      float4 sB = *(const float4*)(&smT[b][0][kb + 4]);
      float4 eA = *(const float4*)(&smT[b][1][kb]);
      float4 eB = *(const float4*)(&smT[b][1][kb + 4]);
      float4 gA = *(const float4*)(&smT[b][2][kb]);
      float4 gB2 = *(const float4*)(&smT[b][2][kb + 4]);
      float sv[8]  = {sA.x, sA.y, sA.z, sA.w, sB.x, sB.y, sB.z, sB.w};
      float e1v[8] = {eA.x, eA.y, eA.z, eA.w, eB.x, eB.y, eB.z, eB.w};
      float e2v[8] = {gA.x, gA.y, gA.z, gA.w, gB2.x, gB2.y, gB2.z, gB2.w};
      unsigned int mb = ((unsigned int)(mrow >> (ks * 32)) >> (grp * 8)) & 0xffu;
      unsigned int pk[4];
      #pragma unroll
      for (int t2 = 0; t2 < 4; ++t2){
        float w0, w1;
        {
          float tt = s1 + sv[2 * t2];
          float w = (tt > 0.f) ? (f1 * e1v[2 * t2]) : (f02 * e2v[2 * t2]);
          w = ((mb >> (2 * t2)) & 1u) ? w : 0.f;
          den += w; w0 = w;
        }
        {
          float tt = s1 + sv[2 * t2 + 1];
          float w = (tt > 0.f) ? (f1 * e1v[2 * t2 + 1]) : (f02 * e2v[2 * t2 + 1]);
          w = ((mb >> (2 * t2 + 1)) & 1u) ? w : 0.f;
          den += w; w1 = w;
        }
        pk[t2] = __builtin_amdgcn_perm(__float_as_uint(w1), __float_as_uint(w0), 0x07060302u);
      }
      short8 af = *(short8*)pk;
      short8 bf = *(const short8*)(&smB[b][((ks * 4 + grp) * 16 + row16) * 8]);
      acc = __builtin_amdgcn_mfma_f32_16x16x32_bf16(af, bf, acc, 0, 0, 0);
    }
  }
  den += __shfl_xor(den, 16, 64);
  den += __shfl_xor(den, 32, 64);
  if (grp == 0)
    pden[(size_t)(iblk * 64 + wid * 16 + row16) * 16 + split] = den;
  #pragma unroll
  for (int r = 0; r < 4; ++r){
    int n = iblk * 64 + wid * 16 + grp * 4 + r;
    pnum[((size_t)n * 16 + split) * 16 + row16] = acc[r];
  }
}

// ------------------------- K7: combine + elu + log_softmax -----------------
__global__ __launch_bounds__(256) void k_final(const float* __restrict__ pnum,
                                               const float* __restrict__ pden,
                                               float* __restrict__ out){
  int tid = blockIdx.x * 256 + threadIdx.x;   // 65536
  int c = tid & 15;
  int n = tid >> 4;
  float num = 0.f, den = 0.f;
  #pragma unroll
  for (int s = 0; s < 16; ++s){
    num += pnum[((size_t)n * 16 + s) * 16 + c];
    den += pden[(size_t)n * 16 + s];
  }
  float v = num / den;
  v = v > 0.f ? v : (__expf(v) - 1.f);
  float m = v;
  #pragma unroll
  for (int d = 1; d < 16; d <<= 1) m = fmaxf(m, __shfl_xor(m, d, 64));
  float es = __expf(v - m), ss = es;
  #pragma unroll
  for (int d = 1; d < 16; d <<= 1) ss += __shfl_xor(ss, d, 64);
  out[(size_t)n * 16 + c] = v - m - __logf(ss);
}

// ---------------------------------------------------------------------------
extern "C" void kernel_launch(void* const* d_in, const int* in_sizes, int n_in,
                              void* d_out, int out_size, void* d_ws, size_t ws_size,
                              hipStream_t stream){
  (void)in_sizes; (void)n_in; (void)out_size; (void)ws_size;
  const float* x    = (const float*)d_in[0];
  const int*   adj  = (const int*)d_in[1];
  const float* W    = (const float*)d_in[2];
  const float* av   = (const float*)d_in[3];
  const float* Wout = (const float*)d_in[4];
  const float* aout = (const float*)d_in[5];
  float* out = (float*)d_out;
  char* ws = (char*)d_ws;

  // --- persistent ---
  u64*  adjbits = (u64*)(ws + 0x0000000);        // 2 MB
  u16*  whB     = (u16*)(ws + 0x0200000);        // 4 MB
  float* s1raw  = (float*)(ws + 0x0600000);      // 6 x 128 KB tables
  float* e11    = (float*)(ws + 0x0620000);
  float* e102   = (float*)(ws + 0x0640000);
  float* s2raw  = (float*)(ws + 0x0660000);
  float* e21    = (float*)(ws + 0x0680000);
  float* e202   = (float*)(ws + 0x06A0000);
  // --- 16 MB overlap region [0x6C0000, 0x16C0000) ---
  // early phase: xA(4MB) | Whf(8MB) | wB(0.5MB)  -- all dead before k_att1
  // late phase : pnum1 bf16 [4][4096][512] = 16 MB
  u16*  xA   = (u16*)(ws + 0x06C0000);
  float* Whf = (float*)(ws + 0x0AC0000);
  u16*  wB   = (u16*)(ws + 0x12C0000);
  u16*  pnum1 = (u16*)(ws + 0x06C0000);
  // --- late persistent ---
  float* pden1 = (float*)(ws + 0x16C0000);       // 4x8x4096 f32 = 512 KB
  u16*  whoB   = (u16*)(ws + 0x1740000);         // 128 KB
  float* s1o   = (float*)(ws + 0x1760000);       // 6 x 16 KB
  float* e11o  = (float*)(ws + 0x1764000);
  float* e102o = (float*)(ws + 0x1768000);
  float* s2o   = (float*)(ws + 0x176C000);
  float* e21o  = (float*)(ws + 0x1770000);
  float* e202o = (float*)(ws + 0x1774000);
  float* pnum2 = (float*)(ws + 0x1778000);       // 4096x16x16 f32 = 4 MB
  float* pden2 = (float*)(ws + 0x1B78000);       // 4096x16 f32 = 256 KB

  k_adj_pack<<<dim3(4096), dim3(256), 0, stream>>>(adj, adjbits);
  k_pack_in<<<dim3(1152), dim3(256), 0, stream>>>(x, W, xA, wB);
  k_gemm1<<<dim3(64, 8), dim3(256), 0, stream>>>(xA, wB, Whf);
  k_prep1<<<dim3(9216), dim3(256), 0, stream>>>(Whf, av, whB, s1raw, e11, e102, s2raw, e21, e202);
  k_att1<<<dim3(64, 8, 4), dim3(256), 0, stream>>>(whB, adjbits, s1raw, e11, e102, s2raw, e21, e202, pnum1, pden1);
  k_gemm2<<<dim3(256), dim3(256), 0, stream>>>(pnum1, pden1, Wout, aout, whoB, s1o, e11o, e102o, s2o, e21o, e202o);
  k_att2<<<dim3(64, 16), dim3(256), 0, stream>>>(whoB, adjbits, s1o, e11o, e102o, s2o, e21o, e202o, pnum2, pden2);
  k_final<<<dim3(256), dim3(256), 0, stream>>>(pnum2, pden2, out);
}

// Round 3
// 194.114 us; speedup vs baseline: 1.3309x; 1.0723x over previous
//
#include <hip/hip_runtime.h>

// ---------------------------------------------------------------------------
// GAT (2-layer, dense mask) on gfx950 — R3.
// vs R2: max-trick (w = max(f1*e1, f02*e2), no select chain, no s-raw tables),
// mask via 4-entry LDS LUT on packed bf16 pairs, den via MFMA ones-column,
// 2 A-tiles/wave in k_att1, smB stride reverted to conflict-free 512,
// k_prep1 fused into k_gemm1 epilogue (no Whf f32 materialization).
// ---------------------------------------------------------------------------

typedef __attribute__((ext_vector_type(8))) short short8;   // 8 x bf16
typedef __attribute__((ext_vector_type(4))) float f32x4;
typedef unsigned long long u64;
typedef unsigned short u16;
typedef unsigned int u32;

__device__ __forceinline__ u16 f2bf_rne(float f){
  u32 u = __float_as_uint(f);
  return (u16)((u + 0x7fffu + ((u >> 16) & 1u)) >> 16);
}
__device__ __forceinline__ void async16(void* lds, const void* g){
  __builtin_amdgcn_global_load_lds((const __attribute__((address_space(1))) u32*)g,
                                   (__attribute__((address_space(3))) u32*)lds, 16, 0, 0);
}
__device__ __forceinline__ void async4(void* lds, const void* g){
  __builtin_amdgcn_global_load_lds((const __attribute__((address_space(1))) u32*)g,
                                   (__attribute__((address_space(3))) u32*)lds, 4, 0, 0);
}

// ------------------------- K0: adj -> bitmask ------------------------------
__global__ __launch_bounds__(256) void k_adj_pack(const int* __restrict__ adj,
                                                  u64* __restrict__ bits){
  int lane = threadIdx.x & 63;
  int w0 = blockIdx.x * 4 + (threadIdx.x >> 6);       // 0..16383
  #pragma unroll
  for (int k = 0; k < 16; ++k){
    int wid = w0 + k * 16384;
    int i  = wid >> 6;
    int jg = wid & 63;
    int v = adj[(size_t)i * 4096 + (jg << 6) + lane];
    u64 m = __ballot(v != 0);
    if (lane == 0) bits[(size_t)i * 64 + jg] = m;
  }
}

// ------------------------- K1: pack x->A-layout + W->B-layout --------------
__global__ __launch_bounds__(256) void k_pack_in(const float* __restrict__ x,
                                                 const float* __restrict__ W,
                                                 u16* __restrict__ xA,
                                                 u16* __restrict__ wB){
  if (blockIdx.x < 1024){
    int tid = blockIdx.x * 256 + threadIdx.x;         // 262144
    int n = tid & 4095;
    int fg = tid >> 12;
    const float* src = x + (size_t)n * 512 + fg * 8;
    float4 v0 = ((const float4*)src)[0];
    float4 v1 = ((const float4*)src)[1];
    u32 pk[4];
    pk[0] = f2bf_rne(v0.x) | ((u32)f2bf_rne(v0.y) << 16);
    pk[1] = f2bf_rne(v0.z) | ((u32)f2bf_rne(v0.w) << 16);
    pk[2] = f2bf_rne(v1.x) | ((u32)f2bf_rne(v1.y) << 16);
    pk[3] = f2bf_rne(v1.z) | ((u32)f2bf_rne(v1.w) << 16);
    *(uint4*)(xA + ((size_t)fg * 4096 + n) * 8) = *(uint4*)pk;
  } else {
    int tid = (blockIdx.x - 1024) * 256 + threadIdx.x; // 32768
    int o  = tid & 63;
    int fg = (tid >> 6) & 63;
    int h  = tid >> 12;
    const float* src = W + ((size_t)h * 512 + fg * 8) * 64 + o;
    u32 pk[4];
    #pragma unroll
    for (int p = 0; p < 4; ++p){
      u16 lo = f2bf_rne(src[(2 * p) * 64]);
      u16 hi = f2bf_rne(src[(2 * p + 1) * 64]);
      pk[p] = lo | ((u32)hi << 16);
    }
    *(uint4*)(wB + (size_t)h * 32768 + ((size_t)fg * 64 + o) * 8) = *(uint4*)pk;
  }
}

// ------------------------- K2: Wh = x @ W[h]; fused tables + whB pack ------
__global__ __launch_bounds__(256) void k_gemm1(const u16* __restrict__ xA,
                                               const u16* __restrict__ wB,
                                               const float* __restrict__ av,
                                               u16* __restrict__ whB,
                                               float* __restrict__ e11, float* __restrict__ e102,
                                               float* __restrict__ e21, float* __restrict__ e202){
  __shared__ u16 tr[4096];                 // 64 x 64 bf16, whB sub-layout
  int h    = blockIdx.y;
  int nblk = blockIdx.x;
  int lane = threadIdx.x & 63;
  int wid  = threadIdx.x >> 6;
  int row16 = lane & 15, grp = lane >> 4;
  int n0 = nblk * 64;
  int n0w = n0 + wid * 16;
  const u16* wBh = wB + (size_t)h * 32768;
  f32x4 acc[4] = {};
  #pragma unroll 4
  for (int ks = 0; ks < 16; ++ks){
    int fgb = ks * 4 + grp;
    short8 af = *(const short8*)(xA + ((size_t)fgb * 4096 + n0w + row16) * 8);
    #pragma unroll
    for (int nt = 0; nt < 4; ++nt){
      short8 bf = *(const short8*)(wBh + ((size_t)fgb * 64 + nt * 16 + row16) * 8);
      acc[nt] = __builtin_amdgcn_mfma_f32_16x16x32_bf16(af, bf, acc[nt], 0, 0, 0);
    }
  }
  // ---- epilogue 1: score tables (per row i = n0w + grp*4 + r) ----
  float a1v[4], a2v[4];
  #pragma unroll
  for (int nt = 0; nt < 4; ++nt){
    a1v[nt] = av[h * 128 + nt * 16 + row16];
    a2v[nt] = av[h * 128 + 64 + nt * 16 + row16];
  }
  #pragma unroll
  for (int r = 0; r < 4; ++r){
    float p1 = acc[0][r] * a1v[0] + acc[1][r] * a1v[1] + acc[2][r] * a1v[2] + acc[3][r] * a1v[3];
    float p2 = acc[0][r] * a2v[0] + acc[1][r] * a2v[1] + acc[2][r] * a2v[2] + acc[3][r] * a2v[3];
    #pragma unroll
    for (int d = 1; d < 16; d <<= 1){ p1 += __shfl_xor(p1, d, 64); p2 += __shfl_xor(p2, d, 64); }
    if (row16 == 0){
      int idx = h * 4096 + n0w + grp * 4 + r;
      e11[idx]  = __expf(p1); e102[idx] = __expf(0.2f * p1);
      e21[idx]  = __expf(p2); e202[idx] = __expf(0.2f * p2);
    }
  }
  // ---- epilogue 2: whB bf16 pack via LDS transpose ----
  #pragma unroll
  for (int nt = 0; nt < 4; ++nt)
    #pragma unroll
    for (int r = 0; r < 4; ++r){
      int jl = wid * 16 + grp * 4 + r;       // local row 0..63
      int o  = nt * 16 + row16;
      tr[((jl >> 3) * 64 + o) * 8 + (jl & 7)] = f2bf_rne(acc[nt][r]);
    }
  __syncthreads();
  u16* dst = whB + (size_t)h * 262144 + (size_t)n0 * 64;
  #pragma unroll
  for (int q = 0; q < 2; ++q)
    *(uint4*)(dst + (threadIdx.x * 2 + q) * 8) = *(const uint4*)(tr + (threadIdx.x * 2 + q) * 8);
}

// ------------------------- K3: layer-1 attention ---------------------------
// grid (32 iblk, 8 h, 4 split); wave = 2 A-tiles (32 i); chunk = 64 j.
__global__ __launch_bounds__(256) void k_att1(const u16* __restrict__ whB,
                                              const u64* __restrict__ adjbits,
                                              const float* __restrict__ e11, const float* __restrict__ e102,
                                              const float* __restrict__ e21, const float* __restrict__ e202,
                                              u16* __restrict__ pnum, float* __restrict__ pden){
  __shared__ u16  smB[2][4096];            // 64 j x 64 o, [j/8][o][j&7], stride 512
  __shared__ float smT[2][2][64];          // e21, e202
  __shared__ u32  smLut[4];
  int h     = blockIdx.y;
  int iblk  = blockIdx.x;
  int split = blockIdx.z;
  int lane = threadIdx.x & 63;
  int wid  = threadIdx.x >> 6;
  int row16 = lane & 15, grp = lane >> 4;
  if (threadIdx.x < 4)
    smLut[threadIdx.x] = ((threadIdx.x & 1) ? 0xFFFFu : 0u) | ((threadIdx.x & 2) ? 0xFFFF0000u : 0u);
  int ibase = iblk * 128 + wid * 32;
  int i0 = ibase + row16, i1 = ibase + 16 + row16;
  int hoff = h * 4096;
  float f1a  = e11[hoff + i0],  f1b  = e11[hoff + i1];
  float f02a = e102[hoff + i0], f02b = e102[hoff + i1];
  const u16* whBh = whB + (size_t)h * 262144;
  int jbeg = split * 1024;

  // den ones-column B fragment: B[k][0] = 1.0
  short8 bden;
  #pragma unroll
  for (int t = 0; t < 8; ++t) bden[t] = (row16 == 0) ? (short)0x3F80 : (short)0;

  auto stage = [&](int b, int j0){
    const char* g = (const char*)whBh + (size_t)j0 * 128 + wid * 2048 + lane * 16;
    char* l = (char*)(&smB[b][0]) + wid * 2048;
    async16(l, g);
    async16(l + 1024, g + 1024);
    if (wid == 0)      async4(&smT[b][0][0], (const char*)(e21  + hoff + j0) + lane * 4);
    else if (wid == 1) async4(&smT[b][1][0], (const char*)(e202 + hoff + j0) + lane * 4);
  };

  f32x4 acc[2][4] = {};
  f32x4 accden[2] = {};
  stage(0, jbeg);
  for (int c = 0; c < 16; ++c){
    int b = c & 1;
    u64 mrow0 = adjbits[(size_t)i0 * 64 + ((jbeg + c * 64) >> 6)];
    u64 mrow1 = adjbits[(size_t)i1 * 64 + ((jbeg + c * 64) >> 6)];
    __syncthreads();                        // buf b staged; buf b^1 free
    if (c < 15) stage(b ^ 1, jbeg + (c + 1) * 64);
    #pragma unroll
    for (int ks = 0; ks < 2; ++ks){
      int kb = ks * 32 + grp * 8;
      float4 eA = *(const float4*)(&smT[b][0][kb]);
      float4 eB = *(const float4*)(&smT[b][0][kb + 4]);
      float4 gA = *(const float4*)(&smT[b][1][kb]);
      float4 gB = *(const float4*)(&smT[b][1][kb + 4]);
      float e1v[8] = {eA.x, eA.y, eA.z, eA.w, eB.x, eB.y, eB.z, eB.w};
      float e2v[8] = {gA.x, gA.y, gA.z, gA.w, gB.x, gB.y, gB.z, gB.w};
      const u16* bbase = &smB[b][(ks * 4 + grp) * 512];
      short8 bf0 = *(const short8*)(bbase + (0 * 16 + row16) * 8);
      short8 bf1 = *(const short8*)(bbase + (1 * 16 + row16) * 8);
      short8 bf2 = *(const short8*)(bbase + (2 * 16 + row16) * 8);
      short8 bf3 = *(const short8*)(bbase + (3 * 16 + row16) * 8);
      #pragma unroll
      for (int it = 0; it < 2; ++it){
        u64 mrow = it ? mrow1 : mrow0;
        float f1 = it ? f1b : f1a;
        float f02 = it ? f02b : f02a;
        u32 mb = ((u32)(mrow >> (ks * 32)) >> (grp * 8)) & 0xffu;
        u32 pk[4];
        #pragma unroll
        for (int t2 = 0; t2 < 4; ++t2){
          float w0 = fmaxf(f1 * e1v[2 * t2],     f02 * e2v[2 * t2]);
          float w1 = fmaxf(f1 * e1v[2 * t2 + 1], f02 * e2v[2 * t2 + 1]);
          u32 p = __builtin_amdgcn_perm(__float_as_uint(w1), __float_as_uint(w0), 0x07060302u);
          pk[t2] = p & smLut[(mb >> (2 * t2)) & 3u];
        }
        short8 af = *(short8*)pk;
        acc[it][0] = __builtin_amdgcn_mfma_f32_16x16x32_bf16(af, bf0, acc[it][0], 0, 0, 0);
        acc[it][1] = __builtin_amdgcn_mfma_f32_16x16x32_bf16(af, bf1, acc[it][1], 0, 0, 0);
        acc[it][2] = __builtin_amdgcn_mfma_f32_16x16x32_bf16(af, bf2, acc[it][2], 0, 0, 0);
        acc[it][3] = __builtin_amdgcn_mfma_f32_16x16x32_bf16(af, bf3, acc[it][3], 0, 0, 0);
        accden[it] = __builtin_amdgcn_mfma_f32_16x16x32_bf16(af, bden, accden[it], 0, 0, 0);
      }
    }
  }

  #pragma unroll
  for (int it = 0; it < 2; ++it){
    #pragma unroll
    for (int r = 0; r < 4; ++r){
      int n = ibase + it * 16 + grp * 4 + r;
      if (row16 == 0)
        pden[((size_t)split * 8 + h) * 4096 + n] = accden[it][r];
      u16* dst = pnum + ((size_t)split * 4096 + n) * 512 + h * 64 + row16;
      #pragma unroll
      for (int nt = 0; nt < 4; ++nt)
        dst[nt * 16] = f2bf_rne(acc[it][nt][r]);
    }
  }
}

// ------------------------- K5: combine + Who=h@Wout + layer-2 tables -------
__global__ __launch_bounds__(256) void k_gemm2(const u16* __restrict__ pnum,
                                               const float* __restrict__ pden,
                                               const float* __restrict__ Wout,
                                               const float* __restrict__ aout,
                                               u16* __restrict__ whoB,
                                               float* __restrict__ e11o, float* __restrict__ e102o,
                                               float* __restrict__ e21o, float* __restrict__ e202o){
  __shared__ float Wl[8192];                  // 512 x 16
  __shared__ float hrow[16 * 516];            // combined+elu rows, padded stride
  __shared__ float sden[128];                 // den[h][n]
  int n0 = blockIdx.x * 16;
  for (int t = threadIdx.x; t < 8192; t += 256) Wl[t] = Wout[t];
  if (threadIdx.x < 128){
    int hh = threadIdx.x >> 4, nn = threadIdx.x & 15;
    float d = 0.f;
    #pragma unroll
    for (int s = 0; s < 4; ++s) d += pden[((size_t)s * 8 + hh) * 4096 + n0 + nn];
    sden[threadIdx.x] = d;
  }
  __syncthreads();
  {
    int nn = threadIdx.x >> 4;                // row 0..15
    int fc = threadIdx.x & 15;                // 32-f chunk
    int f0 = fc * 32;
    int hh = fc >> 1;
    float dinv = 1.f / sden[hh * 16 + nn];
    float v[32];
    #pragma unroll
    for (int k = 0; k < 32; ++k) v[k] = 0.f;
    #pragma unroll
    for (int s = 0; s < 4; ++s){
      const u16* p = pnum + ((size_t)s * 4096 + n0 + nn) * 512 + f0;
      #pragma unroll
      for (int q = 0; q < 4; ++q){
        uint4 raw = *(const uint4*)(p + q * 8);
        u32 rw[4] = {raw.x, raw.y, raw.z, raw.w};
        #pragma unroll
        for (int d2 = 0; d2 < 4; ++d2){
          v[q * 8 + d2 * 2]     += __uint_as_float(rw[d2] << 16);
          v[q * 8 + d2 * 2 + 1] += __uint_as_float(rw[d2] & 0xffff0000u);
        }
      }
    }
    #pragma unroll
    for (int k = 0; k < 32; ++k){
      float val = v[k] * dinv;
      val = val > 0.f ? val : (__expf(val) - 1.f);
      hrow[nn * 516 + f0 + k] = val;
    }
  }
  __syncthreads();
  int c  = threadIdx.x & 15;
  int rl = threadIdx.x >> 4;                  // 0..15
  int n = n0 + rl;
  const float4* hr = (const float4*)(hrow + rl * 516);
  float acc = 0.f;
  #pragma unroll 8
  for (int f4 = 0; f4 < 128; ++f4){
    float4 hv = hr[f4];
    int f = f4 * 4;
    acc += hv.x * Wl[f * 16 + c] + hv.y * Wl[(f + 1) * 16 + c]
         + hv.z * Wl[(f + 2) * 16 + c] + hv.w * Wl[(f + 3) * 16 + c];
  }
  whoB[((size_t)(n >> 3) * 16 + c) * 8 + (n & 7)] = f2bf_rne(acc);
  float p1 = acc * aout[c], p2 = acc * aout[16 + c];
  #pragma unroll
  for (int d = 1; d < 16; d <<= 1){ p1 += __shfl_xor(p1, d, 64); p2 += __shfl_xor(p2, d, 64); }
  if (c == 0){
    e11o[n] = __expf(p1); e102o[n] = __expf(0.2f * p1);
    e21o[n] = __expf(p2); e202o[n] = __expf(0.2f * p2);
  }
}

// ------------------------- K6: layer-2 attention (16-way split) ------------
__global__ __launch_bounds__(256) void k_att2(const u16* __restrict__ whoB,
                                              const u64* __restrict__ adjbits,
                                              const float* __restrict__ e11o, const float* __restrict__ e102o,
                                              const float* __restrict__ e21o, const float* __restrict__ e202o,
                                              float* __restrict__ pnum, float* __restrict__ pden){
  __shared__ u16  smB[2][1024];
  __shared__ float smT[2][2][64];
  __shared__ u32  smLut[4];
  int iblk  = blockIdx.x;
  int split = blockIdx.y;                     // 0..15
  int lane = threadIdx.x & 63;
  int wid  = threadIdx.x >> 6;
  int row16 = lane & 15, grp = lane >> 4;
  if (threadIdx.x < 4)
    smLut[threadIdx.x] = ((threadIdx.x & 1) ? 0xFFFFu : 0u) | ((threadIdx.x & 2) ? 0xFFFF0000u : 0u);
  int i = iblk * 64 + wid * 16 + row16;
  float f1  = e11o[i];
  float f02 = e102o[i];
  int jbeg = split * 256;
  short8 bden;
  #pragma unroll
  for (int t = 0; t < 8; ++t) bden[t] = (row16 == 0) ? (short)0x3F80 : (short)0;

  auto stage = [&](int b, int j0){
    const char* gB = (const char*)whoB + (size_t)j0 * 32;
    if (wid == 0){
      async16((char*)&smB[b][0], gB + lane * 16);
      async16((char*)&smB[b][0] + 1024, gB + 1024 + lane * 16);
    }
    else if (wid == 1) async4(&smT[b][0][0], (const char*)(e21o  + j0) + lane * 4);
    else if (wid == 2) async4(&smT[b][1][0], (const char*)(e202o + j0) + lane * 4);
  };

  f32x4 acc = {};
  f32x4 accden = {};
  stage(0, jbeg);
  for (int c = 0; c < 4; ++c){
    int b = c & 1;
    u64 mrow = adjbits[(size_t)i * 64 + ((jbeg + c * 64) >> 6)];
    __syncthreads();
    if (c < 3) stage(b ^ 1, jbeg + (c + 1) * 64);
    #pragma unroll
    for (int ks = 0; ks < 2; ++ks){
      int kb = ks * 32 + grp * 8;
      float4 eA = *(const float4*)(&smT[b][0][kb]);
      float4 eB = *(const float4*)(&smT[b][0][kb + 4]);
      float4 gA = *(const float4*)(&smT[b][1][kb]);
      float4 gB = *(const float4*)(&smT[b][1][kb + 4]);
      float e1v[8] = {eA.x, eA.y, eA.z, eA.w, eB.x, eB.y, eB.z, eB.w};
      float e2v[8] = {gA.x, gA.y, gA.z, gA.w, gB.x, gB.y, gB.z, gB.w};
      u32 mb = ((u32)(mrow >> (ks * 32)) >> (grp * 8)) & 0xffu;
      u32 pk[4];
      #pragma unroll
      for (int t2 = 0; t2 < 4; ++t2){
        float w0 = fmaxf(f1 * e1v[2 * t2],     f02 * e2v[2 * t2]);
        float w1 = fmaxf(f1 * e1v[2 * t2 + 1], f02 * e2v[2 * t2 + 1]);
        u32 p = __builtin_amdgcn_perm(__float_as_uint(w1), __float_as_uint(w0), 0x07060302u);
        pk[t2] = p & smLut[(mb >> (2 * t2)) & 3u];
      }
      short8 af = *(short8*)pk;
      short8 bf = *(const short8*)(&smB[b][((ks * 4 + grp) * 16 + row16) * 8]);
      acc    = __builtin_amdgcn_mfma_f32_16x16x32_bf16(af, bf, acc, 0, 0, 0);
      accden = __builtin_amdgcn_mfma_f32_16x16x32_bf16(af, bden, accden, 0, 0, 0);
    }
  }
  #pragma unroll
  for (int r = 0; r < 4; ++r){
    int n = iblk * 64 + wid * 16 + grp * 4 + r;
    if (row16 == 0)
      pden[(size_t)n * 16 + split] = accden[r];
    pnum[((size_t)n * 16 + split) * 16 + row16] = acc[r];
  }
}

// ------------------------- K7: combine + elu + log_softmax -----------------
__global__ __launch_bounds__(256) void k_final(const float* __restrict__ pnum,
                                               const float* __restrict__ pden,
                                               float* __restrict__ out){
  int tid = blockIdx.x * 256 + threadIdx.x;   // 65536
  int c = tid & 15;
  int n = tid >> 4;
  float num = 0.f, den = 0.f;
  #pragma unroll
  for (int s = 0; s < 16; ++s){
    num += pnum[((size_t)n * 16 + s) * 16 + c];
    den += pden[(size_t)n * 16 + s];
  }
  float v = num / den;
  v = v > 0.f ? v : (__expf(v) - 1.f);
  float m = v;
  #pragma unroll
  for (int d = 1; d < 16; d <<= 1) m = fmaxf(m, __shfl_xor(m, d, 64));
  float es = __expf(v - m), ss = es;
  #pragma unroll
  for (int d = 1; d < 16; d <<= 1) ss += __shfl_xor(ss, d, 64);
  out[(size_t)n * 16 + c] = v - m - __logf(ss);
}

// ---------------------------------------------------------------------------
extern "C" void kernel_launch(void* const* d_in, const int* in_sizes, int n_in,
                              void* d_out, int out_size, void* d_ws, size_t ws_size,
                              hipStream_t stream){
  (void)in_sizes; (void)n_in; (void)out_size; (void)ws_size;
  const float* x    = (const float*)d_in[0];
  const int*   adj  = (const int*)d_in[1];
  const float* W    = (const float*)d_in[2];
  const float* av   = (const float*)d_in[3];
  const float* Wout = (const float*)d_in[4];
  const float* aout = (const float*)d_in[5];
  float* out = (float*)d_out;
  char* ws = (char*)d_ws;

  // --- persistent ---
  u64*  adjbits = (u64*)(ws + 0x0000000);        // 2 MB
  u16*  whB     = (u16*)(ws + 0x0200000);        // 4 MB
  float* e11    = (float*)(ws + 0x0600000);      // 4 x 128 KB exp tables
  float* e102   = (float*)(ws + 0x0620000);
  float* e21    = (float*)(ws + 0x0640000);
  float* e202   = (float*)(ws + 0x0660000);
  // --- 16 MB overlap region [0x680000, 0x1680000) ---
  // early: xA (4 MB) @0x680000, wB (512 KB) @0xA80000 — dead before k_att1
  // late : pnum1 bf16 [4][4096][512] = 16 MB
  u16*  xA    = (u16*)(ws + 0x0680000);
  u16*  wB    = (u16*)(ws + 0x0A80000);
  u16*  pnum1 = (u16*)(ws + 0x0680000);
  // --- late persistent ---
  float* pden1 = (float*)(ws + 0x1680000);       // 4x8x4096 f32 = 512 KB
  u16*  whoB   = (u16*)(ws + 0x1700000);         // 128 KB
  float* e11o  = (float*)(ws + 0x1720000);       // 4 x 16 KB
  float* e102o = (float*)(ws + 0x1724000);
  float* e21o  = (float*)(ws + 0x1728000);
  float* e202o = (float*)(ws + 0x172C000);
  float* pnum2 = (float*)(ws + 0x1730000);       // 4096x16x16 f32 = 4 MB
  float* pden2 = (float*)(ws + 0x1B30000);       // 4096x16 f32 = 256 KB

  k_adj_pack<<<dim3(4096), dim3(256), 0, stream>>>(adj, adjbits);
  k_pack_in<<<dim3(1152), dim3(256), 0, stream>>>(x, W, xA, wB);
  k_gemm1<<<dim3(64, 8), dim3(256), 0, stream>>>(xA, wB, av, whB, e11, e102, e21, e202);
  k_att1<<<dim3(32, 8, 4), dim3(256), 0, stream>>>(whB, adjbits, e11, e102, e21, e202, pnum1, pden1);
  k_gemm2<<<dim3(256), dim3(256), 0, stream>>>(pnum1, pden1, Wout, aout, whoB, e11o, e102o, e21o, e202o);
  k_att2<<<dim3(64, 16), dim3(256), 0, stream>>>(whoB, adjbits, e11o, e102o, e21o, e202o, pnum2, pden2);
  k_final<<<dim3(256), dim3(256), 0, stream>>>(pnum2, pden2, out);
}